// Round 1
// 959.155 us; speedup vs baseline: 1.2365x; 1.2365x over previous
//
#include <hip/hip_runtime.h>
#include <stdint.h>

// Problem constants (from reference)
#define N_USERS 100000
#define N_ITEMS 50000
#define N_NODES 150000
#define NNZ     4800000
#define DIM     64
#define NELEM   (N_NODES * DIM)   // 9,600,000
#define EPS_F   0.1f

// Invariants established in rounds 0-9:
//  - all inputs f32; outputs f32; out = [all_mean | layer_embeddings]
//  - noise bits = o0 ^ o1 of threefry2x32(fold_in(key42,k), (0, flat_idx));
//    u = bitcast((bits>>9)|0x3f800000) - 1
//  - SpMM must accumulate per-row in ASCENDING EDGE ORDER with separate
//    __fmul_rn/__fadd_rn (matches np f32 sequential scatter-add; sign()
//    amplifies any reassociation into 0.02-scale errors)
//  - row L2-norm association is NOT load-bearing
//  - R8: hops are latency-bound -> MLP spmm (lane-parallel pairs, 4x gathers)
//  - R9 (this round): collect was 430us of scatter/atomic overhead (296MB
//    writes vs 38MB ideal, VALUBusy 0.33%). Replaced collect+sortk with a
//    deterministic 4-stage binning pipeline (hist/scan/scatter/group_sort):
//    zero global atomics, L2-local writes, bucketed-CSR output. Final pairs
//    are bit-identical (rank-sort by edge id canonicalizes race order).

#define NBUCK  768     // row buckets
#define RPB    196     // rows per bucket (768*196 = 150,528 >= 150,000)
#define BCAP   6752    // entry cap per bucket (mean 6250, +6.3 sigma)
#define CHUNK  8192    // edges per chunk block
#define NCHUNK 586     // ceil(NNZ / CHUNK); 585*8192=4,792,320, last=7,680

// entry packing: e[0:23) | col[23:41) | lrow[41:49)
#define E_MASK   0x7FFFFFu
#define COL_MASK 0x3FFFFu

typedef unsigned long long ull;

// ---------------------------------------------------------------------------
// JAX threefry2x32
// ---------------------------------------------------------------------------
__host__ __device__ inline void threefry2x32_fn(unsigned k0, unsigned k1,
                                                unsigned x0, unsigned x1,
                                                unsigned* o0, unsigned* o1) {
  unsigned ks0 = k0, ks1 = k1, ks2 = k0 ^ k1 ^ 0x1BD11BDAu;
  x0 += ks0; x1 += ks1;
#define TF_ROUND(r) { x0 += x1; x1 = (x1 << (r)) | (x1 >> (32 - (r))); x1 ^= x0; }
  TF_ROUND(13) TF_ROUND(15) TF_ROUND(26) TF_ROUND(6)
  x0 += ks1; x1 += ks2 + 1u;
  TF_ROUND(17) TF_ROUND(29) TF_ROUND(16) TF_ROUND(24)
  x0 += ks2; x1 += ks0 + 2u;
  TF_ROUND(13) TF_ROUND(15) TF_ROUND(26) TF_ROUND(6)
  x0 += ks0; x1 += ks1 + 3u;
  TF_ROUND(17) TF_ROUND(29) TF_ROUND(16) TF_ROUND(24)
  x0 += ks1; x1 += ks2 + 4u;
  TF_ROUND(13) TF_ROUND(15) TF_ROUND(26) TF_ROUND(6)
  x0 += ks2; x1 += ks0 + 5u;
#undef TF_ROUND
  *o0 = x0; *o1 = x1;
}

// ---------------------------------------------------------------------------
// K1: per-(chunk,bucket) histogram via LDS counters. counts[c*NBUCK + b].
// ---------------------------------------------------------------------------
__global__ void hist_kernel(const int* __restrict__ rows,
                            int* __restrict__ counts) {
  __shared__ int h[NBUCK];
  int c = blockIdx.x, tid = threadIdx.x;
  for (int t = tid; t < NBUCK; t += 256) h[t] = 0;
  __syncthreads();
  int cb = c * CHUNK;
  #pragma unroll
  for (int k = 0; k < CHUNK / 256; ++k) {
    int i = cb + k * 256 + tid;
    if (i < NNZ) {
      int r = rows[i];
      atomicAdd(&h[r / RPB], 1);
    }
  }
  __syncthreads();
  for (int t = tid; t < NBUCK; t += 256)
    counts[c * NBUCK + t] = h[t];
}

// ---------------------------------------------------------------------------
// K2: per-bucket exclusive prefix over chunks (768 threads = 3 blocks).
// base[c*NBUCK + b] = start slot of chunk c's entries within bucket b.
// ---------------------------------------------------------------------------
__global__ void scan_kernel(const int* __restrict__ counts,
                            int* __restrict__ base,
                            int* __restrict__ btot) {
  int b = blockIdx.x * 256 + threadIdx.x;   // 0..767 exact
  int run = 0;
  #pragma unroll 8
  for (int c = 0; c < NCHUNK; ++c) {
    int v = counts[c * NBUCK + b];
    base[c * NBUCK + b] = run;
    run += v;
  }
  btot[b] = run;
}

// ---------------------------------------------------------------------------
// K3: deterministic-range scatter. Each chunk block preloads its slot bases
// into LDS, then appends packed (lrow|col|e) entries. No global atomics;
// writes cluster into ~dense runs per bucket region (L2/L3-absorbed).
// Order within a (chunk,bucket) range is racy — canonicalized by K4's sort.
// ---------------------------------------------------------------------------
__global__ void scatter_kernel(const int* __restrict__ rows,
                               const int* __restrict__ cols,
                               const int* __restrict__ base,
                               ull* __restrict__ staging) {
  __shared__ int cur[NBUCK];
  int c = blockIdx.x, tid = threadIdx.x;
  for (int t = tid; t < NBUCK; t += 256) cur[t] = base[c * NBUCK + t];
  __syncthreads();
  int cb = c * CHUNK;
  #pragma unroll
  for (int k = 0; k < CHUNK / 256; ++k) {
    int i = cb + k * 256 + tid;
    if (i < NNZ) {
      int r  = rows[i];
      int cc = cols[i];
      int b  = r / RPB;
      int lr = r - b * RPB;
      int p  = atomicAdd(&cur[b], 1);
      if (p < BCAP)
        staging[(long long)b * BCAP + p] =
            ((ull)(unsigned)lr << 41) | ((ull)(unsigned)cc << 23) | (unsigned)i;
    }
  }
}

// ---------------------------------------------------------------------------
// K4: one block per bucket. Count rows -> scan -> group entries by row in
// LDS -> rank-sort each row by edge id (ascending; preserves the load-bearing
// accumulation order) -> gather vals[e] -> overwrite staging in place with
// final (col<<32)|val pairs in bucketed-CSR layout. Writes cnt/off.
// ---------------------------------------------------------------------------
__global__ void group_sort_kernel(const float* __restrict__ vals,
                                  const int* __restrict__ btot,
                                  ull* __restrict__ staging,
                                  int* __restrict__ cnt,
                                  int* __restrict__ off) {
  __shared__ ull B[BCAP];                  // 54,016 B
  __shared__ int rowcnt[RPB];
  __shared__ int rowoff[RPB + 1];
  __shared__ int rowcur[RPB];
  int b = blockIdx.x, tid = threadIdx.x;
  int tot = btot[b]; if (tot > BCAP) tot = BCAP;
  ull* sg = staging + (long long)b * BCAP;

  for (int t = tid; t < RPB; t += 256) { rowcnt[t] = 0; rowcur[t] = 0; }
  __syncthreads();

  // Phase A: per-row counts
  for (int s = tid; s < tot; s += 256) {
    ull v = sg[s];
    atomicAdd(&rowcnt[(int)(v >> 41)], 1);
  }
  __syncthreads();

  // Phase B: exclusive scan over 196 rows (serial; trivial vs block work)
  if (tid == 0) {
    int run = 0;
    for (int t = 0; t < RPB; ++t) { rowoff[t] = run; run += rowcnt[t]; }
    rowoff[RPB] = run;
  }
  __syncthreads();

  // cnt/off for this bucket's rows
  int row0 = b * RPB;
  for (int t = tid; t < RPB; t += 256) {
    int r = row0 + t;
    if (r < N_NODES) { cnt[r] = rowcnt[t]; off[r] = b * BCAP + rowoff[t]; }
  }

  // Phase C: group entries by row into LDS (order within row still racy)
  for (int s = tid; s < tot; s += 256) {
    ull v = sg[s];
    int lr = (int)(v >> 41);
    int p = atomicAdd(&rowcur[lr], 1);
    B[rowoff[lr] + p] = v;
  }
  __syncthreads();

  // Phase D: rank by edge id within row (unique e -> bijection), gather val,
  // write final pair at its sorted slot. In-place over staging is safe:
  // all sg reads completed in Phase C (barrier above).
  for (int s = tid; s < tot; s += 256) {
    ull v = B[s];
    int lr = (int)(v >> 41);
    unsigned e = (unsigned)(v & E_MASK);
    int lo = rowoff[lr], hi = rowoff[lr + 1];
    int rk = 0;
    for (int j = lo; j < hi; ++j)
      rk += ((unsigned)(B[j] & E_MASK) < e) ? 1 : 0;
    float val = vals[e];                   // one-time random gather (L3-hot)
    unsigned col = (unsigned)((v >> 23) & COL_MASK);
    sg[lo + rk] = ((ull)col << 32) | __float_as_uint(val);
  }
}

// ---------------------------------------------------------------------------
// K5-7: fused SpMM + noise + output epilogue (bucketed-CSR indexing).
// One wave per row, lane = dim. Pairs read once lane-parallel, broadcast via
// __shfl; gathers unrolled 4x; strict-order __fadd_rn chain unchanged.
// ---------------------------------------------------------------------------
template <int K>
__global__ void spmm_noise_kernel(const ull* __restrict__ pairs,
                                  const int* __restrict__ cnt,
                                  const int* __restrict__ off,
                                  const float* __restrict__ user_e,
                                  const float* __restrict__ item_e,
                                  const float* __restrict__ src,
                                  float* __restrict__ dst,
                                  float* __restrict__ out_mean,
                                  unsigned key0, unsigned key1) {
  int wid  = threadIdx.x >> 6;
  int lane = threadIdx.x & 63;
  int row  = blockIdx.x * 4 + wid;          // grid covers N_NODES exactly
  int d = cnt[row]; if (d > 128) d = 128;   // realized max deg ~70
  const ull* prow = pairs + off[row];

  // row's pairs -> registers (coalesced; slots >= d never consumed; reads
  // stay inside the staging allocation: max off+127 < NBUCK*BCAP)
  ull my0 = prow[lane];
  ull my1 = prow[64 + lane];

  #define GET_PAIR(t) ((t) < 64 ? __shfl(my0, (t), 64) : __shfl(my1, (t) - 64, 64))

  #define GATHER(c, xout_) do {                                            \
    if (K == 0) {                                                          \
      xout_ = ((c) < N_USERS)                                              \
          ? user_e[(long long)(c) * DIM + lane]                            \
          : item_e[(long long)((c) - N_USERS) * DIM + lane];               \
    } else {                                                               \
      xout_ = src[(long long)(c) * DIM + lane];                            \
    }                                                                      \
  } while (0)

  float acc = 0.0f;
  int t = 0;
  for (; t + 4 <= d; t += 4) {
    ull p0 = GET_PAIR(t);
    ull p1 = GET_PAIR(t + 1);
    ull p2 = GET_PAIR(t + 2);
    ull p3 = GET_PAIR(t + 3);
    int c0 = (int)(unsigned)(p0 >> 32), c1 = (int)(unsigned)(p1 >> 32);
    int c2 = (int)(unsigned)(p2 >> 32), c3 = (int)(unsigned)(p3 >> 32);
    float x0, x1, x2, x3;
    GATHER(c0, x0); GATHER(c1, x1); GATHER(c2, x2); GATHER(c3, x3);
    float v0 = __uint_as_float((unsigned)(p0 & 0xffffffffu));
    float v1 = __uint_as_float((unsigned)(p1 & 0xffffffffu));
    float v2 = __uint_as_float((unsigned)(p2 & 0xffffffffu));
    float v3 = __uint_as_float((unsigned)(p3 & 0xffffffffu));
    acc = __fadd_rn(acc, __fmul_rn(v0, x0));   // strict ascending edge order
    acc = __fadd_rn(acc, __fmul_rn(v1, x1));
    acc = __fadd_rn(acc, __fmul_rn(v2, x2));
    acc = __fadd_rn(acc, __fmul_rn(v3, x3));
  }
  for (; t < d; ++t) {
    ull p = GET_PAIR(t);
    int c = (int)(unsigned)(p >> 32);
    float x;
    GATHER(c, x);
    float v = __uint_as_float((unsigned)(p & 0xffffffffu));
    acc = __fadd_rn(acc, __fmul_rn(v, x));
  }
  #undef GATHER
  #undef GET_PAIR

  // --- noise epilogue (exact JAX stream; norm association not load-bearing)
  int i = row * DIM + lane;
  unsigned o0, o1;
  threefry2x32_fn(key0, key1, 0u, (unsigned)i, &o0, &o1);
  unsigned bits = o0 ^ o1;
  float u = __uint_as_float((bits >> 9) | 0x3f800000u) - 1.0f;
  float ss = __fmul_rn(u, u);
  #pragma unroll
  for (int offs = 32; offs >= 1; offs >>= 1)
    ss += __shfl_xor(ss, offs, 64);
  float noise = u / sqrtf(ss);
  float s = (acc > 0.0f) ? 1.0f : ((acc < 0.0f) ? -1.0f : 0.0f);
  float val = __fadd_rn(acc, __fmul_rn(s, __fmul_rn(noise, EPS_F)));

  if (K == 0) {
    dst[i] = val;                           // dst == out_layer (hop-0 ego)
    out_mean[i] = val;
  } else if (K == 1) {
    dst[i] = val;                           // ws ego buffer for hop 2
    out_mean[i] = __fadd_rn(out_mean[i], val);
  } else {
    out_mean[i] = __fadd_rn(out_mean[i], val) / 3.0f;
  }
}

// ---------------------------------------------------------------------------
// Launch
// ---------------------------------------------------------------------------
extern "C" void kernel_launch(void* const* d_in, const int* in_sizes, int n_in,
                              void* d_out, int out_size, void* d_ws, size_t ws_size,
                              hipStream_t stream) {
  const float* user_e = (const float*)d_in[0];
  const float* item_e = (const float*)d_in[1];
  const int*   rows   = (const int*)d_in[2];
  const int*   cols   = (const int*)d_in[3];
  const float* vals   = (const float*)d_in[4];

  float* out_mean  = (float*)d_out;           // [all_mean: 150000 x 64]
  float* out_layer = (float*)d_out + NELEM;   // [layer_embeddings] == hop-0 ego

  // workspace layout (84.7 MB total):
  //   staging/pairs 41,484,288 | counts 1,800,192 | base 1,800,192 |
  //   btot 3,072 | cnt 600,000 | off 600,000 | ego 38,400,000
  char* w = (char*)d_ws;
  ull*   staging = (ull*)w;
  int*   counts  = (int*)(w + 41484288);
  int*   basep   = (int*)(w + 43284480);
  int*   btot    = (int*)(w + 45084672);
  int*   cnt     = (int*)(w + 45087744);
  int*   off     = (int*)(w + 45687744);
  float* ego     = (float*)(w + 46287744);

  // fold_in(key(42), k) = threefry((0,42),(0,k))
  unsigned hk0[3], hk1[3];
  for (int k = 0; k < 3; ++k)
    threefry2x32_fn(0u, 42u, 0u, (unsigned)k, &hk0[k], &hk1[k]);

  const int BT = 256;
  const unsigned row_blocks = N_NODES / 4;    // 37500 exact (4 rows/block)

  hist_kernel<<<NCHUNK, BT, 0, stream>>>(rows, counts);
  scan_kernel<<<NBUCK / BT, BT, 0, stream>>>(counts, basep, btot);
  scatter_kernel<<<NCHUNK, BT, 0, stream>>>(rows, cols, basep, staging);
  group_sort_kernel<<<NBUCK, BT, 0, stream>>>(vals, btot, staging, cnt, off);

  spmm_noise_kernel<0><<<row_blocks, BT, 0, stream>>>(
      staging, cnt, off, user_e, item_e, nullptr, out_layer, out_mean, hk0[0], hk1[0]);
  spmm_noise_kernel<1><<<row_blocks, BT, 0, stream>>>(
      staging, cnt, off, nullptr, nullptr, out_layer, ego, out_mean, hk0[1], hk1[1]);
  spmm_noise_kernel<2><<<row_blocks, BT, 0, stream>>>(
      staging, cnt, off, nullptr, nullptr, ego, nullptr, out_mean, hk0[2], hk1[2]);
}

// Round 3
// 946.870 us; speedup vs baseline: 1.2526x; 1.0130x over previous
//
#include <hip/hip_runtime.h>
#include <stdint.h>

// Problem constants (from reference)
#define N_USERS 100000
#define N_ITEMS 50000
#define N_NODES 150000
#define NNZ     4800000
#define DIM     64
#define NELEM   (N_NODES * DIM)   // 9,600,000
#define EPS_F   0.1f

// Invariants established in rounds 0-11:
//  - all inputs f32; outputs f32; out = [all_mean | layer_embeddings]
//  - noise bits = o0 ^ o1 of threefry2x32(fold_in(key42,k), (0, flat_idx));
//    u = bitcast((bits>>9)|0x3f800000) - 1
//  - SpMM must accumulate per-row in ASCENDING EDGE ORDER with separate
//    __fmul_rn/__fadd_rn (matches np f32 sequential scatter-add; sign()
//    amplifies any reassociation into 0.02-scale errors)
//  - row L2-norm association is NOT load-bearing
//  - R9: collect/sortk replaced by deterministic 4-stage binning
//    (hist/scan/scatter/group_sort); bucketed-CSR pairs, zero global atomics
//  - R10: hops were VALU-bound (73% VALUBusy, 42% HBM) on ds_bpermute
//    broadcasts + 128-pair/row overfetch. Scalarized the per-row pair
//    stream (readfirstlane -> s_load path), uniform-clamped 8-wide gather
//    unroll. Accumulation chain bit-identical.
//  - R11 (this round): R10's bench failed on infra (container acquire/push
//    stall; prior round already showed 735s npz push). Kernel unchanged —
//    resubmitting to get the R10 measurement.

#define NBUCK  768     // row buckets
#define RPB    196     // rows per bucket (768*196 = 150,528 >= 150,000)
#define BCAP   6752    // entry cap per bucket (mean 6250, +6.3 sigma)
#define CHUNK  8192    // edges per chunk block
#define NCHUNK 586     // ceil(NNZ / CHUNK); 585*8192=4,792,320, last=7,680

// entry packing: e[0:23) | col[23:41) | lrow[41:49)
#define E_MASK   0x7FFFFFu
#define COL_MASK 0x3FFFFu

typedef unsigned long long ull;

// ---------------------------------------------------------------------------
// JAX threefry2x32
// ---------------------------------------------------------------------------
__host__ __device__ inline void threefry2x32_fn(unsigned k0, unsigned k1,
                                                unsigned x0, unsigned x1,
                                                unsigned* o0, unsigned* o1) {
  unsigned ks0 = k0, ks1 = k1, ks2 = k0 ^ k1 ^ 0x1BD11BDAu;
  x0 += ks0; x1 += ks1;
#define TF_ROUND(r) { x0 += x1; x1 = (x1 << (r)) | (x1 >> (32 - (r))); x1 ^= x0; }
  TF_ROUND(13) TF_ROUND(15) TF_ROUND(26) TF_ROUND(6)
  x0 += ks1; x1 += ks2 + 1u;
  TF_ROUND(17) TF_ROUND(29) TF_ROUND(16) TF_ROUND(24)
  x0 += ks2; x1 += ks0 + 2u;
  TF_ROUND(13) TF_ROUND(15) TF_ROUND(26) TF_ROUND(6)
  x0 += ks0; x1 += ks1 + 3u;
  TF_ROUND(17) TF_ROUND(29) TF_ROUND(16) TF_ROUND(24)
  x0 += ks1; x1 += ks2 + 4u;
  TF_ROUND(13) TF_ROUND(15) TF_ROUND(26) TF_ROUND(6)
  x0 += ks2; x1 += ks0 + 5u;
#undef TF_ROUND
  *o0 = x0; *o1 = x1;
}

// ---------------------------------------------------------------------------
// K1: per-(chunk,bucket) histogram via LDS counters. counts[c*NBUCK + b].
// ---------------------------------------------------------------------------
__global__ void hist_kernel(const int* __restrict__ rows,
                            int* __restrict__ counts) {
  __shared__ int h[NBUCK];
  int c = blockIdx.x, tid = threadIdx.x;
  for (int t = tid; t < NBUCK; t += 256) h[t] = 0;
  __syncthreads();
  int cb = c * CHUNK;
  #pragma unroll
  for (int k = 0; k < CHUNK / 256; ++k) {
    int i = cb + k * 256 + tid;
    if (i < NNZ) {
      int r = rows[i];
      atomicAdd(&h[r / RPB], 1);
    }
  }
  __syncthreads();
  for (int t = tid; t < NBUCK; t += 256)
    counts[c * NBUCK + t] = h[t];
}

// ---------------------------------------------------------------------------
// K2: per-bucket exclusive prefix over chunks (768 threads = 3 blocks).
// base[c*NBUCK + b] = start slot of chunk c's entries within bucket b.
// ---------------------------------------------------------------------------
__global__ void scan_kernel(const int* __restrict__ counts,
                            int* __restrict__ base,
                            int* __restrict__ btot) {
  int b = blockIdx.x * 256 + threadIdx.x;   // 0..767 exact
  int run = 0;
  #pragma unroll 8
  for (int c = 0; c < NCHUNK; ++c) {
    int v = counts[c * NBUCK + b];
    base[c * NBUCK + b] = run;
    run += v;
  }
  btot[b] = run;
}

// ---------------------------------------------------------------------------
// K3: deterministic-range scatter. Each chunk block preloads its slot bases
// into LDS, then appends packed (lrow|col|e) entries. No global atomics;
// writes cluster into ~dense runs per bucket region (L2/L3-absorbed).
// Order within a (chunk,bucket) range is racy — canonicalized by K4's sort.
// ---------------------------------------------------------------------------
__global__ void scatter_kernel(const int* __restrict__ rows,
                               const int* __restrict__ cols,
                               const int* __restrict__ base,
                               ull* __restrict__ staging) {
  __shared__ int cur[NBUCK];
  int c = blockIdx.x, tid = threadIdx.x;
  for (int t = tid; t < NBUCK; t += 256) cur[t] = base[c * NBUCK + t];
  __syncthreads();
  int cb = c * CHUNK;
  #pragma unroll
  for (int k = 0; k < CHUNK / 256; ++k) {
    int i = cb + k * 256 + tid;
    if (i < NNZ) {
      int r  = rows[i];
      int cc = cols[i];
      int b  = r / RPB;
      int lr = r - b * RPB;
      int p  = atomicAdd(&cur[b], 1);
      if (p < BCAP)
        staging[(long long)b * BCAP + p] =
            ((ull)(unsigned)lr << 41) | ((ull)(unsigned)cc << 23) | (unsigned)i;
    }
  }
}

// ---------------------------------------------------------------------------
// K4: one block per bucket. Count rows -> scan -> group entries by row in
// LDS -> rank-sort each row by edge id (ascending; preserves the load-bearing
// accumulation order) -> gather vals[e] -> overwrite staging in place with
// final (col<<32)|val pairs in bucketed-CSR layout. Writes cnt/off.
// ---------------------------------------------------------------------------
__global__ void group_sort_kernel(const float* __restrict__ vals,
                                  const int* __restrict__ btot,
                                  ull* __restrict__ staging,
                                  int* __restrict__ cnt,
                                  int* __restrict__ off) {
  __shared__ ull B[BCAP];                  // 54,016 B
  __shared__ int rowcnt[RPB];
  __shared__ int rowoff[RPB + 1];
  __shared__ int rowcur[RPB];
  int b = blockIdx.x, tid = threadIdx.x;
  int tot = btot[b]; if (tot > BCAP) tot = BCAP;
  ull* sg = staging + (long long)b * BCAP;

  for (int t = tid; t < RPB; t += 256) { rowcnt[t] = 0; rowcur[t] = 0; }
  __syncthreads();

  // Phase A: per-row counts
  for (int s = tid; s < tot; s += 256) {
    ull v = sg[s];
    atomicAdd(&rowcnt[(int)(v >> 41)], 1);
  }
  __syncthreads();

  // Phase B: exclusive scan over 196 rows (serial; trivial vs block work)
  if (tid == 0) {
    int run = 0;
    for (int t = 0; t < RPB; ++t) { rowoff[t] = run; run += rowcnt[t]; }
    rowoff[RPB] = run;
  }
  __syncthreads();

  // cnt/off for this bucket's rows
  int row0 = b * RPB;
  for (int t = tid; t < RPB; t += 256) {
    int r = row0 + t;
    if (r < N_NODES) { cnt[r] = rowcnt[t]; off[r] = b * BCAP + rowoff[t]; }
  }

  // Phase C: group entries by row into LDS (order within row still racy)
  for (int s = tid; s < tot; s += 256) {
    ull v = sg[s];
    int lr = (int)(v >> 41);
    int p = atomicAdd(&rowcur[lr], 1);
    B[rowoff[lr] + p] = v;
  }
  __syncthreads();

  // Phase D: rank by edge id within row (unique e -> bijection), gather val,
  // write final pair at its sorted slot. In-place over staging is safe:
  // all sg reads completed in Phase C (barrier above).
  for (int s = tid; s < tot; s += 256) {
    ull v = B[s];
    int lr = (int)(v >> 41);
    unsigned e = (unsigned)(v & E_MASK);
    int lo = rowoff[lr], hi = rowoff[lr + 1];
    int rk = 0;
    for (int j = lo; j < hi; ++j)
      rk += ((unsigned)(B[j] & E_MASK) < e) ? 1 : 0;
    float val = vals[e];                   // one-time random gather (L3-hot)
    unsigned col = (unsigned)((v >> 23) & COL_MASK);
    sg[lo + rk] = ((ull)col << 32) | __float_as_uint(val);
  }
}

// ---------------------------------------------------------------------------
// K5-7: fused SpMM + noise + output epilogue, SCALARIZED pair stream.
// One wave per row, lane = dim. row/cnt/off forced uniform via readfirstlane
// so pair reads lower to s_load (scalar cache, no VALU, no vmcnt), col
// extraction and user/item select become scalar ops, and each gather is
// global_load_dword v, v(lane*4), s[base]. 8 gathers in flight; indices
// uniformly clamped to d-1 with invalid vals zeroed (adding +0.0 is exact),
// so there is no serial tail. Strict ascending-edge __fadd_rn chain intact.
// ---------------------------------------------------------------------------
template <int K>
__global__ void spmm_noise_kernel(const ull* __restrict__ pairs,
                                  const int* __restrict__ cnt,
                                  const int* __restrict__ off,
                                  const float* __restrict__ user_e,
                                  const float* __restrict__ item_e,
                                  const float* __restrict__ src,
                                  float* __restrict__ dst,
                                  float* __restrict__ out_mean,
                                  unsigned key0, unsigned key1) {
  int wid  = threadIdx.x >> 6;
  int lane = threadIdx.x & 63;
  int row  = blockIdx.x * 4 + wid;          // grid covers N_NODES exactly
  int row_u = __builtin_amdgcn_readfirstlane(row);   // wave-uniform SGPR
  int d = cnt[row_u];                       // uniform -> s_load
  if (d > 128) d = 128;                     // realized max deg ~70
  const ull* prow = pairs + off[row_u];     // uniform SGPR base

  #define GATHER(c, xout_) do {                                            \
    if (K == 0) {                                                          \
      const float* bp_ = ((c) < N_USERS)                                   \
          ? user_e + (long long)(c) * DIM                                  \
          : item_e + (long long)((c) - N_USERS) * DIM;                     \
      xout_ = bp_[lane];                                                   \
    } else {                                                               \
      xout_ = src[(long long)(c) * DIM + lane];                            \
    }                                                                      \
  } while (0)

  float acc = 0.0f;
  for (int t = 0; t < d; t += 8) {          // d>=1 whenever loop runs
    int i0 = t,     i1 = t + 1, i2 = t + 2, i3 = t + 3;
    int i4 = t + 4, i5 = t + 5, i6 = t + 6, i7 = t + 7;
    int dm1 = d - 1;
    if (i1 > dm1) i1 = dm1;  if (i2 > dm1) i2 = dm1;  if (i3 > dm1) i3 = dm1;
    if (i4 > dm1) i4 = dm1;  if (i5 > dm1) i5 = dm1;  if (i6 > dm1) i6 = dm1;
    if (i7 > dm1) i7 = dm1;
    ull p0 = prow[i0], p1 = prow[i1], p2 = prow[i2], p3 = prow[i3];
    ull p4 = prow[i4], p5 = prow[i5], p6 = prow[i6], p7 = prow[i7];
    int c0 = (int)(unsigned)(p0 >> 32), c1 = (int)(unsigned)(p1 >> 32);
    int c2 = (int)(unsigned)(p2 >> 32), c3 = (int)(unsigned)(p3 >> 32);
    int c4 = (int)(unsigned)(p4 >> 32), c5 = (int)(unsigned)(p5 >> 32);
    int c6 = (int)(unsigned)(p6 >> 32), c7 = (int)(unsigned)(p7 >> 32);
    float x0, x1, x2, x3, x4, x5, x6, x7;
    GATHER(c0, x0); GATHER(c1, x1); GATHER(c2, x2); GATHER(c3, x3);
    GATHER(c4, x4); GATHER(c5, x5); GATHER(c6, x6); GATHER(c7, x7);
    float v0 = __uint_as_float((unsigned)(p0 & 0xffffffffu));
    float v1 = (t + 1 < d) ? __uint_as_float((unsigned)(p1 & 0xffffffffu)) : 0.0f;
    float v2 = (t + 2 < d) ? __uint_as_float((unsigned)(p2 & 0xffffffffu)) : 0.0f;
    float v3 = (t + 3 < d) ? __uint_as_float((unsigned)(p3 & 0xffffffffu)) : 0.0f;
    float v4 = (t + 4 < d) ? __uint_as_float((unsigned)(p4 & 0xffffffffu)) : 0.0f;
    float v5 = (t + 5 < d) ? __uint_as_float((unsigned)(p5 & 0xffffffffu)) : 0.0f;
    float v6 = (t + 6 < d) ? __uint_as_float((unsigned)(p6 & 0xffffffffu)) : 0.0f;
    float v7 = (t + 7 < d) ? __uint_as_float((unsigned)(p7 & 0xffffffffu)) : 0.0f;
    // strict ascending edge order; v==0 lanes add exact +0.0 (x finite)
    acc = __fadd_rn(acc, __fmul_rn(v0, x0));
    acc = __fadd_rn(acc, __fmul_rn(v1, x1));
    acc = __fadd_rn(acc, __fmul_rn(v2, x2));
    acc = __fadd_rn(acc, __fmul_rn(v3, x3));
    acc = __fadd_rn(acc, __fmul_rn(v4, x4));
    acc = __fadd_rn(acc, __fmul_rn(v5, x5));
    acc = __fadd_rn(acc, __fmul_rn(v6, x6));
    acc = __fadd_rn(acc, __fmul_rn(v7, x7));
  }
  #undef GATHER

  // --- noise epilogue (exact JAX stream; norm association not load-bearing)
  int i = row * DIM + lane;
  unsigned o0, o1;
  threefry2x32_fn(key0, key1, 0u, (unsigned)i, &o0, &o1);
  unsigned bits = o0 ^ o1;
  float u = __uint_as_float((bits >> 9) | 0x3f800000u) - 1.0f;
  float ss = __fmul_rn(u, u);
  #pragma unroll
  for (int offs = 32; offs >= 1; offs >>= 1)
    ss += __shfl_xor(ss, offs, 64);
  float noise = u / sqrtf(ss);
  float s = (acc > 0.0f) ? 1.0f : ((acc < 0.0f) ? -1.0f : 0.0f);
  float val = __fadd_rn(acc, __fmul_rn(s, __fmul_rn(noise, EPS_F)));

  if (K == 0) {
    dst[i] = val;                           // dst == out_layer (hop-0 ego)
    out_mean[i] = val;
  } else if (K == 1) {
    dst[i] = val;                           // ws ego buffer for hop 2
    out_mean[i] = __fadd_rn(out_mean[i], val);
  } else {
    out_mean[i] = __fadd_rn(out_mean[i], val) / 3.0f;
  }
}

// ---------------------------------------------------------------------------
// Launch
// ---------------------------------------------------------------------------
extern "C" void kernel_launch(void* const* d_in, const int* in_sizes, int n_in,
                              void* d_out, int out_size, void* d_ws, size_t ws_size,
                              hipStream_t stream) {
  const float* user_e = (const float*)d_in[0];
  const float* item_e = (const float*)d_in[1];
  const int*   rows   = (const int*)d_in[2];
  const int*   cols   = (const int*)d_in[3];
  const float* vals   = (const float*)d_in[4];

  float* out_mean  = (float*)d_out;           // [all_mean: 150000 x 64]
  float* out_layer = (float*)d_out + NELEM;   // [layer_embeddings] == hop-0 ego

  // workspace layout (84.7 MB total):
  //   staging/pairs 41,484,288 | counts 1,800,192 | base 1,800,192 |
  //   btot 3,072 | cnt 600,000 | off 600,000 | ego 38,400,000
  char* w = (char*)d_ws;
  ull*   staging = (ull*)w;
  int*   counts  = (int*)(w + 41484288);
  int*   basep   = (int*)(w + 43284480);
  int*   btot    = (int*)(w + 45084672);
  int*   cnt     = (int*)(w + 45087744);
  int*   off     = (int*)(w + 45687744);
  float* ego     = (float*)(w + 46287744);

  // fold_in(key(42), k) = threefry((0,42),(0,k))
  unsigned hk0[3], hk1[3];
  for (int k = 0; k < 3; ++k)
    threefry2x32_fn(0u, 42u, 0u, (unsigned)k, &hk0[k], &hk1[k]);

  const int BT = 256;
  const unsigned row_blocks = N_NODES / 4;    // 37500 exact (4 rows/block)

  hist_kernel<<<NCHUNK, BT, 0, stream>>>(rows, counts);
  scan_kernel<<<NBUCK / BT, BT, 0, stream>>>(counts, basep, btot);
  scatter_kernel<<<NCHUNK, BT, 0, stream>>>(rows, cols, basep, staging);
  group_sort_kernel<<<NBUCK, BT, 0, stream>>>(vals, btot, staging, cnt, off);

  spmm_noise_kernel<0><<<row_blocks, BT, 0, stream>>>(
      staging, cnt, off, user_e, item_e, nullptr, out_layer, out_mean, hk0[0], hk1[0]);
  spmm_noise_kernel<1><<<row_blocks, BT, 0, stream>>>(
      staging, cnt, off, nullptr, nullptr, out_layer, ego, out_mean, hk0[1], hk1[1]);
  spmm_noise_kernel<2><<<row_blocks, BT, 0, stream>>>(
      staging, cnt, off, nullptr, nullptr, ego, nullptr, out_mean, hk0[2], hk1[2]);
}